// Round 2
// baseline (1006.441 us; speedup 1.0000x reference)
//
#include <hip/hip_runtime.h>

#define L_DIM 128
#define BB 8          // real batch rows per block (padded to 16 for MFMA)

typedef _Float16 f16;
typedef _Float16 f16x8 __attribute__((ext_vector_type(8)));
typedef float f32x4 __attribute__((ext_vector_type(4)));

__device__ __forceinline__ float fast_tanh(float x) {
    // tanh(x) = 1 - 2/(1+e^{2x}); e^{2x} = 2^{x*2*log2(e)}
    float e = __builtin_amdgcn_exp2f(x * 2.8853900817779268f);
    float r = __builtin_amdgcn_rcpf(e + 1.0f);
    return fmaf(-2.0f, r, 1.0f);   // large +x -> 1; large -x -> -1
}

__global__ void __launch_bounds__(1024, 4)
cde_kernel(const float* __restrict__ coeffs,
           const float* __restrict__ W_init, const float* __restrict__ b_init,
           const float* __restrict__ W1, const float* __restrict__ b1,
           const float* __restrict__ W2, const float* __restrict__ b2,
           const float* __restrict__ W_out, const float* __restrict__ b_out,
           float* __restrict__ out)
{
    // Strides: z16 row = 72 f16 = 9 granules (odd), h16 row = 136 f16 = 17 granules (odd)
    // -> ds_read_b128 granule-group = (lr+q) mod 8, even 8-lane spread = conflict-free.
    __shared__ __align__(16) f16   z16[16][72];        // fp16 z (rows 8-15 = 0 pad, static)
    __shared__ __align__(16) f16   h16[16][136];       // fp16 hidden activations
    __shared__ __align__(16) float dxT[2][3][16][20];  // [buf][which][c][b]; b 8..19 = 0
    __shared__ __align__(16) float zf[BB][64];         // epilogue gather

    const int tid  = threadIdx.x;
    const int blk  = blockIdx.x;
    const int lane = tid & 63;
    const int w    = tid >> 6;        // wave 0..15
    const int q    = lane >> 4;       // quarter-wave 0..3
    const int lr   = lane & 15;
    // GEMM2 column permutation: col lr of tile t4 -> (hh = w*4 + (lr&3), c = 4*t4 + (lr>>2))
    // => c-sum = accumulate over t4 (register) + shfl_xor(4) + shfl_xor(8). No LDS reduce.
    const int hh   = w * 4 + (lr & 3);
    const int cq   = lr >> 2;

    // ---- one-time: weight fragments into registers ----
    f16x8 w2f[4][4];
#pragma unroll
    for (int t4 = 0; t4 < 4; ++t4)
#pragma unroll
        for (int kc = 0; kc < 4; ++kc) {
            const float* src = W2 + (size_t)(hh * 16 + 4 * t4 + cq) * 128 + kc * 32 + q * 8;
            f16x8 v;
#pragma unroll
            for (int i = 0; i < 8; ++i) v[i] = (f16)src[i];
            w2f[t4][kc] = v;
        }
    float b2r[4];
#pragma unroll
    for (int t4 = 0; t4 < 4; ++t4) b2r[t4] = b2[hh * 16 + 4 * t4 + cq];

    f16x8 w1f[2];
    float b1r = 0.f;
    if (w < 8) {
#pragma unroll
        for (int kc = 0; kc < 2; ++kc) {
            const float* src = W1 + (size_t)(w * 16 + lr) * 64 + kc * 32 + q * 8;
            f16x8 v;
#pragma unroll
            for (int i = 0; i < 8; ++i) v[i] = (f16)src[i];
            w1f[kc] = v;
        }
        b1r = b1[w * 16 + lr];
    }

    // ---- init: z0 = X0 @ W_init^T + b_init, held in registers per (b = q*4+r, hh) ----
    float z32r[4] = {0.f, 0.f, 0.f, 0.f};
    float ksumr[4] = {0.f, 0.f, 0.f, 0.f};
    if (q < 2) {
#pragma unroll
        for (int r = 0; r < 4; ++r) {
            const int b = q * 4 + r;
            const float* x0 = coeffs + (size_t)(blk * BB + b) * (L_DIM - 1) * 64;
            float acc = b_init[hh];
#pragma unroll
            for (int c = 0; c < 16; ++c) acc = fmaf(x0[c], W_init[hh * 16 + c], acc);
            z32r[r] = acc;
        }
    }
    if (q < 2 && lr < 4) {
#pragma unroll
        for (int r = 0; r < 4; ++r) z16[q * 4 + r][hh] = (f16)z32r[r];
    }
    for (int i = tid; i < 8 * 72; i += 1024) z16[8 + i / 72][i % 72] = (f16)0.f;  // pad rows
    for (int i = tid; i < 2 * 3 * 16 * 12; i += 1024) {                            // pad b cols
        int bf = i / (3 * 16 * 12), rem = i % (3 * 16 * 12);
        dxT[bf][rem / (16 * 12)][(rem / 12) % 16][8 + (rem % 12)] = 0.f;
    }
    // spline derivs for step 0 into buffer 0
    if (tid < BB * 16) {
        const int b = tid >> 4, c = tid & 15;
        const float* seg = coeffs + (size_t)(blk * BB + b) * (L_DIM - 1) * 64;
        float bv = seg[16 + c], cv = seg[32 + c], dv = seg[48 + c];
        dxT[0][0][c][b] = bv;
        dxT[0][1][c][b] = fmaf(0.25f, dv, fmaf(0.5f, cv, bv));
        dxT[0][2][c][b] = seg[64 + 16 + c];
    }
    __syncthreads();

    // ---- main loop: 127 RK4 steps x 4 f-evals, 2 barriers per f-eval ----
    for (int t = 0; t < L_DIM - 1; ++t) {
        const int buf = t & 1;
#pragma unroll
        for (int s = 0; s < 4; ++s) {
            // Phase A: GEMM1 on waves 0-7 (h = relu(z @ W1^T + b1)); prefetch on waves 8-9
            if (w < 8) {
                f16x8 za0 = *(const f16x8*)&z16[lr][q * 8];
                f16x8 za1 = *(const f16x8*)&z16[lr][32 + q * 8];
                f32x4 hacc = {0.f, 0.f, 0.f, 0.f};
                hacc = __builtin_amdgcn_mfma_f32_16x16x32_f16(za0, w1f[0], hacc, 0, 0, 0);
                hacc = __builtin_amdgcn_mfma_f32_16x16x32_f16(za1, w1f[1], hacc, 0, 0, 0);
#pragma unroll
                for (int r = 0; r < 4; ++r)
                    h16[q * 4 + r][w * 16 + lr] = (f16)fmaxf(hacc[r] + b1r, 0.f);
            } else if (s == 0 && t < L_DIM - 2) {
                const int pt = tid - 512;
                if (pt < BB * 16) {
                    const int b = pt >> 4, c = pt & 15;
                    const float* seg = coeffs + ((size_t)(blk * BB + b) * (L_DIM - 1) + (t + 1)) * 64;
                    float bv = seg[16 + c], cv = seg[32 + c], dv2 = seg[48 + c];
                    dxT[buf ^ 1][0][c][b] = bv;
                    dxT[buf ^ 1][1][c][b] = fmaf(0.25f, dv2, fmaf(0.5f, cv, bv));
                    dxT[buf ^ 1][2][c][b] = (t + 1 < L_DIM - 2) ? seg[64 + 16 + c]
                                                                : (bv + cv + dv2);
                }
            }
            __syncthreads();

            // Phase B: GEMM2 + tanh + dX contraction + in-register RK4
            const int ds = (s == 0) ? 0 : ((s == 3) ? 2 : 1);
            f32x4 acc[4] = {{0.f,0.f,0.f,0.f},{0.f,0.f,0.f,0.f},{0.f,0.f,0.f,0.f},{0.f,0.f,0.f,0.f}};
            __builtin_amdgcn_s_setprio(1);
#pragma unroll
            for (int kc = 0; kc < 4; ++kc) {
                f16x8 af = *(const f16x8*)&h16[lr][kc * 32 + q * 8];
#pragma unroll
                for (int t4 = 0; t4 < 4; ++t4)
                    acc[t4] = __builtin_amdgcn_mfma_f32_16x16x32_f16(af, w2f[t4][kc], acc[t4], 0, 0, 0);
            }
            __builtin_amdgcn_s_setprio(0);
            float ka[4] = {0.f, 0.f, 0.f, 0.f};
#pragma unroll
            for (int t4 = 0; t4 < 4; ++t4) {
                f32x4 dv = *(const f32x4*)&dxT[buf][ds][4 * t4 + cq][q * 4];  // 4-lane broadcast
#pragma unroll
                for (int r = 0; r < 4; ++r)
                    ka[r] = fmaf(fast_tanh(acc[t4][r] + b2r[t4]), dv[r], ka[r]);
            }
#pragma unroll
            for (int r = 0; r < 4; ++r) {
                ka[r] += __shfl_xor(ka[r], 4);
                ka[r] += __shfl_xor(ka[r], 8);     // full k[b][hh] in every lane
            }
            // RK4 stage update, fully in registers (q>=2 lanes carry harmless zeros)
#pragma unroll
            for (int r = 0; r < 4; ++r) {
                float k = ka[r], zs;
                if (s == 0)      { ksumr[r] = k;           zs = fmaf(0.5f, k, z32r[r]); }
                else if (s == 1) { ksumr[r] += 2.f * k;    zs = fmaf(0.5f, k, z32r[r]); }
                else if (s == 2) { ksumr[r] += 2.f * k;    zs = z32r[r] + k; }
                else { z32r[r] = fmaf(ksumr[r] + k, 1.f / 6.f, z32r[r]); zs = z32r[r]; }
                if (q < 2 && lr < 4) z16[q * 4 + r][hh] = (f16)zs;
            }
            __syncthreads();
        }
    }

    // ---- epilogue: out = zT @ W_out^T + b_out ----
    if (q < 2 && lr < 4) {
#pragma unroll
        for (int r = 0; r < 4; ++r) zf[q * 4 + r][hh] = z32r[r];
    }
    __syncthreads();
    if (tid < 64) {
        const int b = lane >> 3, j0 = lane & 7;
        float p = 0.f;
#pragma unroll
        for (int m = 0; m < 8; ++m) p += zf[b][j0 + 8 * m] * W_out[j0 + 8 * m];
        p += __shfl_xor(p, 1, 64);
        p += __shfl_xor(p, 2, 64);
        p += __shfl_xor(p, 4, 64);
        if (j0 == 0) out[blk * BB + b] = p + b_out[0];
    }
}

extern "C" void kernel_launch(void* const* d_in, const int* in_sizes, int n_in,
                              void* d_out, int out_size, void* d_ws, size_t ws_size,
                              hipStream_t stream) {
    const float* coeffs = (const float*)d_in[0];
    const float* W_init = (const float*)d_in[1];
    const float* b_init = (const float*)d_in[2];
    const float* W1     = (const float*)d_in[3];
    const float* b1     = (const float*)d_in[4];
    const float* W2     = (const float*)d_in[5];
    const float* b2     = (const float*)d_in[6];
    const float* W_out  = (const float*)d_in[7];
    const float* b_out  = (const float*)d_in[8];
    cde_kernel<<<256, 1024, 0, stream>>>(coeffs, W_init, b_init, W1, b1, W2, b2,
                                         W_out, b_out, (float*)d_out);
}